// Round 5
// baseline (632.896 us; speedup 1.0000x reference)
//
#include <hip/hip_runtime.h>
#include <math.h>

#define D_MODEL 512
#define NHEADS 8
#define DK 64
#define DFFN 2048

typedef __attribute__((ext_vector_type(8))) __bf16 bf16x8;
typedef __attribute__((ext_vector_type(4))) float floatx4;
typedef __attribute__((ext_vector_type(4))) float fvec4;

// ============ prep: weight casts (y=0..5) + bias pack (y=6) + LN1 (y=7) ============
struct Seg { const float* src; __bf16* dst; int n4; };  // n4 = n/4
struct Segs6 { Seg s[6]; };

__global__ __launch_bounds__(256) void prep(Segs6 cs,
    const float* __restrict__ bq, const float* __restrict__ bk,
    const float* __restrict__ bv, float* __restrict__ bqkv,
    const float* __restrict__ x, const float* __restrict__ alpha,
    const float* __restrict__ beta, __bf16* __restrict__ y_out, int rows) {
  int y = blockIdx.y;
  if (y == 7) {
    // LayerNorm: one wave per row, shuffle-reduce
    if (blockIdx.x >= (rows >> 2)) return;
    int w = threadIdx.x >> 6, lane = threadIdx.x & 63;
    int row = blockIdx.x * 4 + w;
    const float* xr = x + (size_t)row * D_MODEL + lane * 8;
    fvec4 v0 = *(const fvec4*)xr;
    fvec4 v1 = *(const fvec4*)(xr + 4);
    float sm = v0.x + v0.y + v0.z + v0.w + v1.x + v1.y + v1.z + v1.w;
    float qd = v0.x * v0.x + v0.y * v0.y + v0.z * v0.z + v0.w * v0.w +
               v1.x * v1.x + v1.y * v1.y + v1.z * v1.z + v1.w * v1.w;
    for (int m = 1; m < 64; m <<= 1) {
      sm += __shfl_xor(sm, m);
      qd += __shfl_xor(qd, m);
    }
    float mu = sm * (1.0f / D_MODEL);
    // ddof=1 variance; denominator (sd + eps) matches jnp.std + EPS
    float var = (qd - (float)D_MODEL * mu * mu) * (1.0f / (D_MODEL - 1));
    float inv = 1.0f / (sqrtf(fmaxf(var, 0.0f)) + 1e-6f);
    fvec4 a0 = *(const fvec4*)(alpha + lane * 8);
    fvec4 a1 = *(const fvec4*)(alpha + lane * 8 + 4);
    fvec4 b0 = *(const fvec4*)(beta + lane * 8);
    fvec4 b1 = *(const fvec4*)(beta + lane * 8 + 4);
    union { __bf16 h[8]; uint4 u4; } pk;
    pk.h[0] = (__bf16)(a0.x * (v0.x - mu) * inv + b0.x);
    pk.h[1] = (__bf16)(a0.y * (v0.y - mu) * inv + b0.y);
    pk.h[2] = (__bf16)(a0.z * (v0.z - mu) * inv + b0.z);
    pk.h[3] = (__bf16)(a0.w * (v0.w - mu) * inv + b0.w);
    pk.h[4] = (__bf16)(a1.x * (v1.x - mu) * inv + b1.x);
    pk.h[5] = (__bf16)(a1.y * (v1.y - mu) * inv + b1.y);
    pk.h[6] = (__bf16)(a1.z * (v1.z - mu) * inv + b1.z);
    pk.h[7] = (__bf16)(a1.w * (v1.w - mu) * inv + b1.w);
    *(uint4*)(y_out + (size_t)row * D_MODEL + lane * 8) = pk.u4;
    return;
  }
  if (y == 6) {
    int idx = blockIdx.x * 256 + threadIdx.x;
    if (idx < 3 * D_MODEL) {
      float v = idx < 512 ? bq[idx] : (idx < 1024 ? bk[idx - 512] : bv[idx - 1024]);
      bqkv[idx] = v;
    }
    return;
  }
  Seg sg = cs.s[y];
  int stride = gridDim.x * 256;
  for (int idx = blockIdx.x * 256 + threadIdx.x; idx < sg.n4; idx += stride) {
    float4 f = ((const float4*)sg.src)[idx];
    union { __bf16 h[4]; uint2 u; } pk;
    pk.h[0] = (__bf16)f.x; pk.h[1] = (__bf16)f.y;
    pk.h[2] = (__bf16)f.z; pk.h[3] = (__bf16)f.w;
    ((uint2*)sg.dst)[idx] = pk.u;
  }
}

// ============ Wave-level bf16 MFMA GEMM ============
// C[m,n] = sum_k A[m,k] * B[n,k] + bias[n] (+ res) (opt relu, opt bf16 out)
// One wave (64 thr) per 32x32 tile, 2x2 fragments of 16x16x32.
// Layout (m89/m91-verified): A-frag lane holds A[m=lane&15][k=quad*8+j];
// B-frag from row n of B (== B^T col); D: col=lane&15, row=quad*4+reg.
template <int RELU, int OUT_BF16>
__global__ __launch_bounds__(64) void wave_gemm(
    const __bf16* __restrict__ A, int lda, const __bf16* __restrict__ B, int ldb,
    const float* __restrict__ bias, const float* __restrict__ res,
    void* __restrict__ Cv, int N, int K) {
  int lane = threadIdx.x;
  int r16 = lane & 15;
  int ko = (lane >> 4) * 8;
  int m0 = blockIdx.y * 32, n0 = blockIdx.x * 32;
  const __bf16* A0 = A + (size_t)(m0 + r16) * lda + ko;
  const __bf16* A1 = A0 + (size_t)16 * lda;
  const __bf16* B0 = B + (size_t)(n0 + r16) * ldb + ko;
  const __bf16* B1 = B0 + (size_t)16 * ldb;
  floatx4 acc00 = {0.f, 0.f, 0.f, 0.f};
  floatx4 acc01 = acc00, acc10 = acc00, acc11 = acc00;
#pragma unroll 4
  for (int k0 = 0; k0 < K; k0 += 32) {
    bf16x8 a0 = *(const bf16x8*)(A0 + k0);
    bf16x8 a1 = *(const bf16x8*)(A1 + k0);
    bf16x8 b0 = *(const bf16x8*)(B0 + k0);
    bf16x8 b1 = *(const bf16x8*)(B1 + k0);
    acc00 = __builtin_amdgcn_mfma_f32_16x16x32_bf16(a0, b0, acc00, 0, 0, 0);
    acc01 = __builtin_amdgcn_mfma_f32_16x16x32_bf16(a0, b1, acc01, 0, 0, 0);
    acc10 = __builtin_amdgcn_mfma_f32_16x16x32_bf16(a1, b0, acc10, 0, 0, 0);
    acc11 = __builtin_amdgcn_mfma_f32_16x16x32_bf16(a1, b1, acc11, 0, 0, 0);
  }
  int col = lane & 15, rb = (lane >> 4) * 4;
  floatx4 accs[2][2] = {{acc00, acc01}, {acc10, acc11}};
#pragma unroll
  for (int i = 0; i < 2; ++i) {
#pragma unroll
    for (int j = 0; j < 2; ++j) {
#pragma unroll
      for (int r = 0; r < 4; ++r) {
        int row = m0 + i * 16 + rb + r;
        int cc = n0 + j * 16 + col;
        float v = accs[i][j][r] + bias[cc];
        if (res) v += res[(size_t)row * N + cc];
        if (RELU) v = fmaxf(v, 0.0f);
        if (OUT_BF16)
          ((__bf16*)Cv)[(size_t)row * N + cc] = (__bf16)v;
        else
          ((float*)Cv)[(size_t)row * N + cc] = v;
      }
    }
  }
}

// ============ wo_ln: Wo GEMM + bias + residual(x) -> xres, then LN2 -> x2b ============
// One block per 32 output rows, 512 threads (8 waves). Wave w owns cols
// [w*64, w*64+64): 2x4 fragments of 16x16x32 over K=512. Result staged in
// LDS (stride 516 floats -> conflict-free), then per-row LN (wave per 4 rows).
__global__ __launch_bounds__(512) void wo_ln(
    const __bf16* __restrict__ conc, const __bf16* __restrict__ Wo,
    const float* __restrict__ bo, const float* __restrict__ x,
    const float* __restrict__ alpha, const float* __restrict__ beta,
    float* __restrict__ xres, __bf16* __restrict__ x2b) {
  constexpr int LW = D_MODEL + 4;  // 516: %32==4 -> epilogue stores 2-way (free)
  __shared__ float sm[32][LW];
  int t = threadIdx.x, w = t >> 6, lane = t & 63;
  int bm = blockIdx.x * 32;
  int r16 = lane & 15, ko = (lane >> 4) * 8;
  const __bf16* A0 = conc + (size_t)(bm + r16) * D_MODEL + ko;
  const __bf16* A1 = A0 + (size_t)16 * D_MODEL;
  int n0 = w * 64;
  const __bf16* B0 = Wo + (size_t)(n0 + r16) * D_MODEL + ko;
  floatx4 acc[2][4];
#pragma unroll
  for (int i = 0; i < 2; ++i)
#pragma unroll
    for (int jc = 0; jc < 4; ++jc) acc[i][jc] = {0.f, 0.f, 0.f, 0.f};
#pragma unroll 4
  for (int k0 = 0; k0 < D_MODEL; k0 += 32) {
    bf16x8 a0 = *(const bf16x8*)(A0 + k0);
    bf16x8 a1 = *(const bf16x8*)(A1 + k0);
#pragma unroll
    for (int jc = 0; jc < 4; ++jc) {
      bf16x8 b = *(const bf16x8*)(B0 + (size_t)jc * 16 * D_MODEL + k0);
      acc[0][jc] = __builtin_amdgcn_mfma_f32_16x16x32_bf16(a0, b, acc[0][jc], 0, 0, 0);
      acc[1][jc] = __builtin_amdgcn_mfma_f32_16x16x32_bf16(a1, b, acc[1][jc], 0, 0, 0);
    }
  }
  int col = lane & 15, rb = (lane >> 4) * 4;
#pragma unroll
  for (int i = 0; i < 2; ++i) {
#pragma unroll
    for (int jc = 0; jc < 4; ++jc) {
#pragma unroll
      for (int r = 0; r < 4; ++r) {
        int row = i * 16 + rb + r;          // local 0..31
        int cc = n0 + jc * 16 + col;        // 0..511
        float v = acc[i][jc][r] + bo[cc] + x[(size_t)(bm + row) * D_MODEL + cc];
        xres[(size_t)(bm + row) * D_MODEL + cc] = v;
        sm[row][cc] = v;
      }
    }
  }
  __syncthreads();
  // LN2: wave w handles rows w*4 .. w*4+3; lane covers 8 floats of the row
#pragma unroll
  for (int rr = 0; rr < 4; ++rr) {
    int row = w * 4 + rr;
    fvec4 v0 = *(const fvec4*)&sm[row][lane * 8];
    fvec4 v1 = *(const fvec4*)&sm[row][lane * 8 + 4];
    float smm = v0.x + v0.y + v0.z + v0.w + v1.x + v1.y + v1.z + v1.w;
    float qd = v0.x * v0.x + v0.y * v0.y + v0.z * v0.z + v0.w * v0.w +
               v1.x * v1.x + v1.y * v1.y + v1.z * v1.z + v1.w * v1.w;
    for (int m = 1; m < 64; m <<= 1) {
      smm += __shfl_xor(smm, m);
      qd += __shfl_xor(qd, m);
    }
    float mu = smm * (1.0f / D_MODEL);
    float var = (qd - (float)D_MODEL * mu * mu) * (1.0f / (D_MODEL - 1));
    float inv = 1.0f / (sqrtf(fmaxf(var, 0.0f)) + 1e-6f);
    fvec4 a0 = *(const fvec4*)(alpha + lane * 8);
    fvec4 a1 = *(const fvec4*)(alpha + lane * 8 + 4);
    fvec4 b0 = *(const fvec4*)(beta + lane * 8);
    fvec4 b1 = *(const fvec4*)(beta + lane * 8 + 4);
    union { __bf16 h[8]; uint4 u4; } pk;
    pk.h[0] = (__bf16)(a0.x * (v0.x - mu) * inv + b0.x);
    pk.h[1] = (__bf16)(a0.y * (v0.y - mu) * inv + b0.y);
    pk.h[2] = (__bf16)(a0.z * (v0.z - mu) * inv + b0.z);
    pk.h[3] = (__bf16)(a0.w * (v0.w - mu) * inv + b0.w);
    pk.h[4] = (__bf16)(a1.x * (v1.x - mu) * inv + b1.x);
    pk.h[5] = (__bf16)(a1.y * (v1.y - mu) * inv + b1.y);
    pk.h[6] = (__bf16)(a1.z * (v1.z - mu) * inv + b1.z);
    pk.h[7] = (__bf16)(a1.w * (v1.w - mu) * inv + b1.w);
    *(uint4*)(x2b + (size_t)(bm + row) * D_MODEL + lane * 8) = pk.u4;
  }
}

// ============ Attention: one block per (b,i), 512 threads (8 waves) ============
// Wave w owns j in [w*32, w*32+32); lane owns d in [lane*8, lane*8+8), head h=lane>>3.
// cbk[b,j,i,:] / cbv[b,j,i,:] are contiguous 2-KB single-use streams -> nt loads.
__global__ __launch_bounds__(512) void attn_kernel(
    const float* __restrict__ qkv, int ldq,
    const float* __restrict__ cbk, const float* __restrict__ cbv,
    const int* __restrict__ mask, __bf16* __restrict__ concat, int s) {
  int i = blockIdx.x % s;
  int b = blockIdx.x / s;
  int t = threadIdx.x;
  int w = t >> 6;        // wave 0..7
  int lane = t & 63;
  int h = lane >> 3;

  __shared__ float sc[NHEADS][257];  // scores then p; 257 -> conflict-free
  __shared__ float sums[NHEADS];
  __shared__ float part[8][D_MODEL];

  size_t tok_i = (size_t)(b * s + i);
  const float* qp = qkv + tok_i * ldq + lane * 8;
  fvec4 q0 = *(const fvec4*)(qp);
  fvec4 q1 = *(const fvec4*)(qp + 4);

  const float* kb  = qkv + (size_t)(b * s) * ldq + 512 + lane * 8;
  const float* cbb = cbk + ((size_t)b * s * s + i) * (size_t)D_MODEL + lane * 8;

  // ---- Phase A: scores[h][j] = (q . (k_j + cbk)) / 8
#pragma unroll 4
  for (int jj = 0; jj < 32; ++jj) {
    int j = w * 32 + jj;
    const float* kp = kb + (size_t)j * ldq;
    const float* cp = cbb + (size_t)j * s * D_MODEL;
    fvec4 k0 = *(const fvec4*)(kp);
    fvec4 k1 = *(const fvec4*)(kp + 4);
    fvec4 c0 = __builtin_nontemporal_load((const fvec4*)cp);
    fvec4 c1 = __builtin_nontemporal_load(((const fvec4*)cp) + 1);
    float d = q0.x * (k0.x + c0.x) + q0.y * (k0.y + c0.y) +
              q0.z * (k0.z + c0.z) + q0.w * (k0.w + c0.w) +
              q1.x * (k1.x + c1.x) + q1.y * (k1.y + c1.y) +
              q1.z * (k1.z + c1.z) + q1.w * (k1.w + c1.w);
    d += __shfl_xor(d, 1);
    d += __shfl_xor(d, 2);
    d += __shfl_xor(d, 4);
    if ((lane & 7) == 0) sc[h][j] = d * 0.125f;
  }
  __syncthreads();

  // ---- Phase S: softmax, wave w handles head w (64 lanes, 4 vals each)
  {
    bool masked = (mask[b * s + i] == 1);
    float vals[4];
    float mx = -1e30f;
#pragma unroll
    for (int kk = 0; kk < 4; ++kk) {
      float xv = sc[w][lane + kk * 64];
      if (masked) xv = -1e9f;
      vals[kk] = xv;
      mx = fmaxf(mx, xv);
    }
    for (int m = 1; m < 64; m <<= 1) mx = fmaxf(mx, __shfl_xor(mx, m));
    float ls = 0.f;
#pragma unroll
    for (int kk = 0; kk < 4; ++kk) {
      float e = expf(vals[kk] - mx);
      sc[w][lane + kk * 64] = e;
      ls += e;
    }
    for (int m = 1; m < 64; m <<= 1) ls += __shfl_xor(ls, m);
    if (lane == 0) sums[w] = ls;
  }
  __syncthreads();

  // ---- Phase B: out[d] = sum_j p[h][j] * (v_j[d] + cbv[d])
  fvec4 a0 = {0.f, 0.f, 0.f, 0.f};
  fvec4 a1 = {0.f, 0.f, 0.f, 0.f};
  const float* vb  = qkv + (size_t)(b * s) * ldq + 1024 + lane * 8;
  const float* cvb = cbv + ((size_t)b * s * s + i) * (size_t)D_MODEL + lane * 8;
#pragma unroll 4
  for (int jj = 0; jj < 32; ++jj) {
    int j = w * 32 + jj;
    const float* vp = vb + (size_t)j * ldq;
    const float* cp = cvb + (size_t)j * s * D_MODEL;
    fvec4 v0 = *(const fvec4*)(vp);
    fvec4 v1 = *(const fvec4*)(vp + 4);
    fvec4 c0 = __builtin_nontemporal_load((const fvec4*)cp);
    fvec4 c1 = __builtin_nontemporal_load(((const fvec4*)cp) + 1);
    float pj = sc[h][j];
    a0.x += pj * (v0.x + c0.x); a0.y += pj * (v0.y + c0.y);
    a0.z += pj * (v0.z + c0.z); a0.w += pj * (v0.w + c0.w);
    a1.x += pj * (v1.x + c1.x); a1.y += pj * (v1.y + c1.y);
    a1.z += pj * (v1.z + c1.z); a1.w += pj * (v1.w + c1.w);
  }
  *(fvec4*)&part[w][lane * 8] = a0;
  *(fvec4*)&part[w][lane * 8 + 4] = a1;
  __syncthreads();

  // ---- Final: reduce 8 waves, scale by 1/sum, write bf16
  if (t < 256) {
    int d0 = t * 2;
    float inv = 1.0f / sums[d0 >> 6];
    float o0 = 0.f, o1 = 0.f;
#pragma unroll
    for (int ww = 0; ww < 8; ++ww) {
      o0 += part[ww][d0];
      o1 += part[ww][d0 + 1];
    }
    union { __bf16 h2[2]; unsigned int u; } pk;
    pk.h2[0] = (__bf16)(o0 * inv);
    pk.h2[1] = (__bf16)(o1 * inv);
    *(unsigned int*)(concat + tok_i * D_MODEL + d0) = pk.u;
  }
}

// ============ Host launch ============
extern "C" void kernel_launch(void* const* d_in, const int* in_sizes, int n_in,
                              void* d_out, int out_size, void* d_ws, size_t ws_size,
                              hipStream_t stream) {
  const float* x      = (const float*)d_in[0];
  const float* cbk    = (const float*)d_in[1];
  const float* cbv    = (const float*)d_in[2];
  const int*   mask   = (const int*)d_in[3];
  const float* Wq     = (const float*)d_in[4];
  const float* bq     = (const float*)d_in[5];
  const float* Wk     = (const float*)d_in[6];
  const float* bk     = (const float*)d_in[7];
  const float* Wv     = (const float*)d_in[8];
  const float* bv     = (const float*)d_in[9];
  const float* Wo     = (const float*)d_in[10];
  const float* bo     = (const float*)d_in[11];
  const float* alpha1 = (const float*)d_in[12];
  const float* beta1  = (const float*)d_in[13];
  const float* alpha2 = (const float*)d_in[14];
  const float* beta2  = (const float*)d_in[15];
  const float* W1     = (const float*)d_in[16];
  const float* b1     = (const float*)d_in[17];
  const float* W2     = (const float*)d_in[18];
  const float* b2     = (const float*)d_in[19];

  int bs = in_sizes[0] / D_MODEL;       // 512 tokens
  int s  = in_sizes[1] / in_sizes[0];   // 256

  // Workspace carve (256-B aligned chunks)
  char* wp = (char*)d_ws;
  auto carve = [&](size_t bytes) {
    char* p = wp;
    wp += (bytes + 255) & ~(size_t)255;
    return p;
  };
  __bf16* x2    = (__bf16*)carve((size_t)bs * D_MODEL * 2);
  __bf16* wqkv  = (__bf16*)carve((size_t)3 * D_MODEL * D_MODEL * 2);
  __bf16* wo_b  = (__bf16*)carve((size_t)D_MODEL * D_MODEL * 2);
  __bf16* w1_b  = (__bf16*)carve((size_t)DFFN * D_MODEL * 2);
  __bf16* w2_b  = (__bf16*)carve((size_t)D_MODEL * DFFN * 2);
  float*  bqkv  = (float*)carve((size_t)3 * D_MODEL * 4);
  float*  qkv   = (float*)carve((size_t)bs * 3 * D_MODEL * 4);
  __bf16* conc  = (__bf16*)carve((size_t)bs * D_MODEL * 2);
  float*  xres  = (float*)carve((size_t)bs * D_MODEL * 4);
  __bf16* x2b   = (__bf16*)carve((size_t)bs * D_MODEL * 2);
  __bf16* f1    = (__bf16*)carve((size_t)bs * DFFN * 2);

  // 1. prep: weights->bf16 (Wq/Wk/Wv packed [1536][512]) + bias pack + LN1
  Segs6 cs;
  cs.s[0] = {Wq, wqkv,                 D_MODEL * D_MODEL / 4};
  cs.s[1] = {Wk, wqkv + D_MODEL * D_MODEL,     D_MODEL * D_MODEL / 4};
  cs.s[2] = {Wv, wqkv + 2 * D_MODEL * D_MODEL, D_MODEL * D_MODEL / 4};
  cs.s[3] = {Wo, wo_b, D_MODEL * D_MODEL / 4};
  cs.s[4] = {W1, w1_b, DFFN * D_MODEL / 4};
  cs.s[5] = {W2, w2_b, D_MODEL * DFFN / 4};
  prep<<<dim3(256, 8), 256, 0, stream>>>(cs, bq, bk, bv, bqkv,
                                         x, alpha1, beta1, x2, bs);

  // 2. Fused QKV GEMM: [512,512] @ [1536,512]^T -> qkv [512][1536] fp32
  wave_gemm<0, 0><<<dim3(3 * D_MODEL / 32, bs / 32), 64, 0, stream>>>(
      x2, D_MODEL, wqkv, D_MODEL, bqkv, nullptr, qkv, 3 * D_MODEL, D_MODEL);

  // 3. Attention (all heads per block, 8 waves) -> concat bf16
  attn_kernel<<<bs, 512, 0, stream>>>(qkv, 3 * D_MODEL, cbk, cbv, mask, conc, s);

  // 4. Wo GEMM + bias + residual(x) -> xres, LN2 -> x2b (fused)
  wo_ln<<<bs / 32, 512, 0, stream>>>(conc, wo_b, bo, x, alpha2, beta2, xres, x2b);

  // 5. FFN1 + ReLU -> f1 bf16
  wave_gemm<1, 1><<<dim3(DFFN / 32, bs / 32), 64, 0, stream>>>(
      x2b, D_MODEL, w1_b, D_MODEL, b1, nullptr, f1, DFFN, D_MODEL);

  // 6. FFN2 + bias + residual(xres) -> d_out fp32
  wave_gemm<0, 0><<<dim3(D_MODEL / 32, bs / 32), 64, 0, stream>>>(
      f1, DFFN, w2_b, DFFN, b2, xres, d_out, D_MODEL, DFFN);
}

// Round 8
// 617.390 us; speedup vs baseline: 1.0251x; 1.0251x over previous
//
#include <hip/hip_runtime.h>
#include <math.h>

#define D_MODEL 512
#define NHEADS 8
#define DK 64
#define DFFN 2048

typedef __attribute__((ext_vector_type(8))) __bf16 bf16x8;
typedef __attribute__((ext_vector_type(4))) float floatx4;
typedef __attribute__((ext_vector_type(4))) float fvec4;

// ============ LayerNorm: one WAVE per row, shuffle-reduce, no LDS ============
__global__ __launch_bounds__(256) void ln_kernel(
    const float* __restrict__ x, const float* __restrict__ alpha,
    const float* __restrict__ beta, __bf16* __restrict__ y) {
  int w = threadIdx.x >> 6, lane = threadIdx.x & 63;
  int row = blockIdx.x * 4 + w;
  const float* xr = x + (size_t)row * D_MODEL + lane * 8;
  fvec4 v0 = *(const fvec4*)xr;
  fvec4 v1 = *(const fvec4*)(xr + 4);
  float sm = v0.x + v0.y + v0.z + v0.w + v1.x + v1.y + v1.z + v1.w;
  float qd = v0.x * v0.x + v0.y * v0.y + v0.z * v0.z + v0.w * v0.w +
             v1.x * v1.x + v1.y * v1.y + v1.z * v1.z + v1.w * v1.w;
  for (int m = 1; m < 64; m <<= 1) {
    sm += __shfl_xor(sm, m);
    qd += __shfl_xor(qd, m);
  }
  float mu = sm * (1.0f / D_MODEL);
  // ddof=1 variance; denominator (sd + eps) matches jnp.std + EPS
  float var = (qd - (float)D_MODEL * mu * mu) * (1.0f / (D_MODEL - 1));
  float inv = 1.0f / (sqrtf(fmaxf(var, 0.0f)) + 1e-6f);
  fvec4 a0 = *(const fvec4*)(alpha + lane * 8);
  fvec4 a1 = *(const fvec4*)(alpha + lane * 8 + 4);
  fvec4 b0 = *(const fvec4*)(beta + lane * 8);
  fvec4 b1 = *(const fvec4*)(beta + lane * 8 + 4);
  union { __bf16 h[8]; uint4 u4; } pk;
  pk.h[0] = (__bf16)(a0.x * (v0.x - mu) * inv + b0.x);
  pk.h[1] = (__bf16)(a0.y * (v0.y - mu) * inv + b0.y);
  pk.h[2] = (__bf16)(a0.z * (v0.z - mu) * inv + b0.z);
  pk.h[3] = (__bf16)(a0.w * (v0.w - mu) * inv + b0.w);
  pk.h[4] = (__bf16)(a1.x * (v1.x - mu) * inv + b1.x);
  pk.h[5] = (__bf16)(a1.y * (v1.y - mu) * inv + b1.y);
  pk.h[6] = (__bf16)(a1.z * (v1.z - mu) * inv + b1.z);
  pk.h[7] = (__bf16)(a1.w * (v1.w - mu) * inv + b1.w);
  *(uint4*)(y + (size_t)row * D_MODEL + lane * 8) = pk.u4;
}

// ============ prep: weight casts (y=0..5) + bias pack (y=6) + LN1 (y=7) ============
struct Seg { const float* src; __bf16* dst; int n4; };  // n4 = n/4
struct Segs6 { Seg s[6]; };

__global__ __launch_bounds__(256) void prep(Segs6 cs,
    const float* __restrict__ bq, const float* __restrict__ bk,
    const float* __restrict__ bv, float* __restrict__ bqkv,
    const float* __restrict__ x, const float* __restrict__ alpha,
    const float* __restrict__ beta, __bf16* __restrict__ y_out, int rows) {
  int y = blockIdx.y;
  if (y == 7) {
    // LayerNorm: one wave per row, shuffle-reduce
    if (blockIdx.x >= (rows >> 2)) return;
    int w = threadIdx.x >> 6, lane = threadIdx.x & 63;
    int row = blockIdx.x * 4 + w;
    const float* xr = x + (size_t)row * D_MODEL + lane * 8;
    fvec4 v0 = *(const fvec4*)xr;
    fvec4 v1 = *(const fvec4*)(xr + 4);
    float sm = v0.x + v0.y + v0.z + v0.w + v1.x + v1.y + v1.z + v1.w;
    float qd = v0.x * v0.x + v0.y * v0.y + v0.z * v0.z + v0.w * v0.w +
               v1.x * v1.x + v1.y * v1.y + v1.z * v1.z + v1.w * v1.w;
    for (int m = 1; m < 64; m <<= 1) {
      sm += __shfl_xor(sm, m);
      qd += __shfl_xor(qd, m);
    }
    float mu = sm * (1.0f / D_MODEL);
    // ddof=1 variance; denominator (sd + eps) matches jnp.std + EPS
    float var = (qd - (float)D_MODEL * mu * mu) * (1.0f / (D_MODEL - 1));
    float inv = 1.0f / (sqrtf(fmaxf(var, 0.0f)) + 1e-6f);
    fvec4 a0 = *(const fvec4*)(alpha + lane * 8);
    fvec4 a1 = *(const fvec4*)(alpha + lane * 8 + 4);
    fvec4 b0 = *(const fvec4*)(beta + lane * 8);
    fvec4 b1 = *(const fvec4*)(beta + lane * 8 + 4);
    union { __bf16 h[8]; uint4 u4; } pk;
    pk.h[0] = (__bf16)(a0.x * (v0.x - mu) * inv + b0.x);
    pk.h[1] = (__bf16)(a0.y * (v0.y - mu) * inv + b0.y);
    pk.h[2] = (__bf16)(a0.z * (v0.z - mu) * inv + b0.z);
    pk.h[3] = (__bf16)(a0.w * (v0.w - mu) * inv + b0.w);
    pk.h[4] = (__bf16)(a1.x * (v1.x - mu) * inv + b1.x);
    pk.h[5] = (__bf16)(a1.y * (v1.y - mu) * inv + b1.y);
    pk.h[6] = (__bf16)(a1.z * (v1.z - mu) * inv + b1.z);
    pk.h[7] = (__bf16)(a1.w * (v1.w - mu) * inv + b1.w);
    *(uint4*)(y_out + (size_t)row * D_MODEL + lane * 8) = pk.u4;
    return;
  }
  if (y == 6) {
    int idx = blockIdx.x * 256 + threadIdx.x;
    if (idx < 3 * D_MODEL) {
      float v = idx < 512 ? bq[idx] : (idx < 1024 ? bk[idx - 512] : bv[idx - 1024]);
      bqkv[idx] = v;
    }
    return;
  }
  Seg sg = cs.s[y];
  int stride = gridDim.x * 256;
  for (int idx = blockIdx.x * 256 + threadIdx.x; idx < sg.n4; idx += stride) {
    float4 f = ((const float4*)sg.src)[idx];
    union { __bf16 h[4]; uint2 u; } pk;
    pk.h[0] = (__bf16)f.x; pk.h[1] = (__bf16)f.y;
    pk.h[2] = (__bf16)f.z; pk.h[3] = (__bf16)f.w;
    ((uint2*)sg.dst)[idx] = pk.u;
  }
}

// ============ Wave-level bf16 MFMA GEMM ============
// C[m,n] = sum_k A[m,k] * B[n,k] + bias[n] (+ res) (opt relu, opt bf16 out)
// One wave (64 thr) per 32x32 tile, 2x2 fragments of 16x16x32.
// A,B L2-resident -> no LDS staging, direct 16-B fragment loads.
// Layout (m89/m91-verified): A-frag lane holds A[m=lane&15][k=quad*8+j];
// B-frag from row n of B (== B^T col); D: col=lane&15, row=quad*4+reg.
template <int RELU, int OUT_BF16>
__global__ __launch_bounds__(64) void wave_gemm(
    const __bf16* __restrict__ A, int lda, const __bf16* __restrict__ B, int ldb,
    const float* __restrict__ bias, const float* __restrict__ res,
    void* __restrict__ Cv, int N, int K) {
  int lane = threadIdx.x;
  int r16 = lane & 15;
  int ko = (lane >> 4) * 8;
  int m0 = blockIdx.y * 32, n0 = blockIdx.x * 32;
  const __bf16* A0 = A + (size_t)(m0 + r16) * lda + ko;
  const __bf16* A1 = A0 + (size_t)16 * lda;
  const __bf16* B0 = B + (size_t)(n0 + r16) * ldb + ko;
  const __bf16* B1 = B0 + (size_t)16 * ldb;
  floatx4 acc00 = {0.f, 0.f, 0.f, 0.f};
  floatx4 acc01 = acc00, acc10 = acc00, acc11 = acc00;
#pragma unroll 4
  for (int k0 = 0; k0 < K; k0 += 32) {
    bf16x8 a0 = *(const bf16x8*)(A0 + k0);
    bf16x8 a1 = *(const bf16x8*)(A1 + k0);
    bf16x8 b0 = *(const bf16x8*)(B0 + k0);
    bf16x8 b1 = *(const bf16x8*)(B1 + k0);
    acc00 = __builtin_amdgcn_mfma_f32_16x16x32_bf16(a0, b0, acc00, 0, 0, 0);
    acc01 = __builtin_amdgcn_mfma_f32_16x16x32_bf16(a0, b1, acc01, 0, 0, 0);
    acc10 = __builtin_amdgcn_mfma_f32_16x16x32_bf16(a1, b0, acc10, 0, 0, 0);
    acc11 = __builtin_amdgcn_mfma_f32_16x16x32_bf16(a1, b1, acc11, 0, 0, 0);
  }
  int col = lane & 15, rb = (lane >> 4) * 4;
  floatx4 accs[2][2] = {{acc00, acc01}, {acc10, acc11}};
#pragma unroll
  for (int i = 0; i < 2; ++i) {
#pragma unroll
    for (int j = 0; j < 2; ++j) {
#pragma unroll
      for (int r = 0; r < 4; ++r) {
        int row = m0 + i * 16 + rb + r;
        int cc = n0 + j * 16 + col;
        float v = accs[i][j][r] + bias[cc];
        if (res) v += res[(size_t)row * N + cc];
        if (RELU) v = fmaxf(v, 0.0f);
        if (OUT_BF16)
          ((__bf16*)Cv)[(size_t)row * N + cc] = (__bf16)v;
        else
          ((float*)Cv)[(size_t)row * N + cc] = v;
      }
    }
  }
}

// ============ Attention: one block per (b,i), 512 threads (8 waves) ============
// Wave w owns j in [w*32, w*32+32); lane owns d in [lane*8, lane*8+8), head h=lane>>3.
// cbk[b,j,i,:] / cbv[b,j,i,:] are contiguous 2-KB single-use streams -> nt loads.
__global__ __launch_bounds__(512) void attn_kernel(
    const float* __restrict__ qkv, int ldq,
    const float* __restrict__ cbk, const float* __restrict__ cbv,
    const int* __restrict__ mask, __bf16* __restrict__ concat, int s) {
  int i = blockIdx.x % s;
  int b = blockIdx.x / s;
  int t = threadIdx.x;
  int w = t >> 6;        // wave 0..7
  int lane = t & 63;
  int h = lane >> 3;

  __shared__ float sc[NHEADS][257];  // scores then p; 257 -> conflict-free
  __shared__ float sums[NHEADS];
  __shared__ float part[8][D_MODEL];

  size_t tok_i = (size_t)(b * s + i);
  const float* qp = qkv + tok_i * ldq + lane * 8;
  fvec4 q0 = *(const fvec4*)(qp);
  fvec4 q1 = *(const fvec4*)(qp + 4);

  const float* kb  = qkv + (size_t)(b * s) * ldq + 512 + lane * 8;
  const float* cbb = cbk + ((size_t)b * s * s + i) * (size_t)D_MODEL + lane * 8;

  // ---- Phase A: scores[h][j] = (q . (k_j + cbk)) / 8
#pragma unroll 4
  for (int jj = 0; jj < 32; ++jj) {
    int j = w * 32 + jj;
    const float* kp = kb + (size_t)j * ldq;
    const float* cp = cbb + (size_t)j * s * D_MODEL;
    fvec4 k0 = *(const fvec4*)(kp);
    fvec4 k1 = *(const fvec4*)(kp + 4);
    fvec4 c0 = __builtin_nontemporal_load((const fvec4*)cp);
    fvec4 c1 = __builtin_nontemporal_load(((const fvec4*)cp) + 1);
    float d = q0.x * (k0.x + c0.x) + q0.y * (k0.y + c0.y) +
              q0.z * (k0.z + c0.z) + q0.w * (k0.w + c0.w) +
              q1.x * (k1.x + c1.x) + q1.y * (k1.y + c1.y) +
              q1.z * (k1.z + c1.z) + q1.w * (k1.w + c1.w);
    d += __shfl_xor(d, 1);
    d += __shfl_xor(d, 2);
    d += __shfl_xor(d, 4);
    if ((lane & 7) == 0) sc[h][j] = d * 0.125f;
  }
  __syncthreads();

  // ---- Phase S: softmax, wave w handles head w (64 lanes, 4 vals each)
  {
    bool masked = (mask[b * s + i] == 1);
    float vals[4];
    float mx = -1e30f;
#pragma unroll
    for (int kk = 0; kk < 4; ++kk) {
      float xv = sc[w][lane + kk * 64];
      if (masked) xv = -1e9f;
      vals[kk] = xv;
      mx = fmaxf(mx, xv);
    }
    for (int m = 1; m < 64; m <<= 1) mx = fmaxf(mx, __shfl_xor(mx, m));
    float ls = 0.f;
#pragma unroll
    for (int kk = 0; kk < 4; ++kk) {
      float e = expf(vals[kk] - mx);
      sc[w][lane + kk * 64] = e;
      ls += e;
    }
    for (int m = 1; m < 64; m <<= 1) ls += __shfl_xor(ls, m);
    if (lane == 0) sums[w] = ls;
  }
  __syncthreads();

  // ---- Phase B: out[d] = sum_j p[h][j] * (v_j[d] + cbv[d])
  fvec4 a0 = {0.f, 0.f, 0.f, 0.f};
  fvec4 a1 = {0.f, 0.f, 0.f, 0.f};
  const float* vb  = qkv + (size_t)(b * s) * ldq + 1024 + lane * 8;
  const float* cvb = cbv + ((size_t)b * s * s + i) * (size_t)D_MODEL + lane * 8;
#pragma unroll 4
  for (int jj = 0; jj < 32; ++jj) {
    int j = w * 32 + jj;
    const float* vp = vb + (size_t)j * ldq;
    const float* cp = cvb + (size_t)j * s * D_MODEL;
    fvec4 v0 = *(const fvec4*)(vp);
    fvec4 v1 = *(const fvec4*)(vp + 4);
    fvec4 c0 = __builtin_nontemporal_load((const fvec4*)cp);
    fvec4 c1 = __builtin_nontemporal_load(((const fvec4*)cp) + 1);
    float pj = sc[h][j];
    a0.x += pj * (v0.x + c0.x); a0.y += pj * (v0.y + c0.y);
    a0.z += pj * (v0.z + c0.z); a0.w += pj * (v0.w + c0.w);
    a1.x += pj * (v1.x + c1.x); a1.y += pj * (v1.y + c1.y);
    a1.z += pj * (v1.z + c1.z); a1.w += pj * (v1.w + c1.w);
  }
  *(fvec4*)&part[w][lane * 8] = a0;
  *(fvec4*)&part[w][lane * 8 + 4] = a1;
  __syncthreads();

  // ---- Final: reduce 8 waves, scale by 1/sum, write bf16
  if (t < 256) {
    int d0 = t * 2;
    float inv = 1.0f / sums[d0 >> 6];
    float o0 = 0.f, o1 = 0.f;
#pragma unroll
    for (int ww = 0; ww < 8; ++ww) {
      o0 += part[ww][d0];
      o1 += part[ww][d0 + 1];
    }
    union { __bf16 h2[2]; unsigned int u; } pk;
    pk.h2[0] = (__bf16)(o0 * inv);
    pk.h2[1] = (__bf16)(o1 * inv);
    *(unsigned int*)(concat + tok_i * D_MODEL + d0) = pk.u;
  }
}

// ============ Host launch ============
extern "C" void kernel_launch(void* const* d_in, const int* in_sizes, int n_in,
                              void* d_out, int out_size, void* d_ws, size_t ws_size,
                              hipStream_t stream) {
  const float* x      = (const float*)d_in[0];
  const float* cbk    = (const float*)d_in[1];
  const float* cbv    = (const float*)d_in[2];
  const int*   mask   = (const int*)d_in[3];
  const float* Wq     = (const float*)d_in[4];
  const float* bq     = (const float*)d_in[5];
  const float* Wk     = (const float*)d_in[6];
  const float* bk     = (const float*)d_in[7];
  const float* Wv     = (const float*)d_in[8];
  const float* bv     = (const float*)d_in[9];
  const float* Wo     = (const float*)d_in[10];
  const float* bo     = (const float*)d_in[11];
  const float* alpha1 = (const float*)d_in[12];
  const float* beta1  = (const float*)d_in[13];
  const float* alpha2 = (const float*)d_in[14];
  const float* beta2  = (const float*)d_in[15];
  const float* W1     = (const float*)d_in[16];
  const float* b1     = (const float*)d_in[17];
  const float* W2     = (const float*)d_in[18];
  const float* b2     = (const float*)d_in[19];

  int bs = in_sizes[0] / D_MODEL;       // 512 tokens
  int s  = in_sizes[1] / in_sizes[0];   // 256

  // Workspace carve (256-B aligned chunks)
  char* wp = (char*)d_ws;
  auto carve = [&](size_t bytes) {
    char* p = wp;
    wp += (bytes + 255) & ~(size_t)255;
    return p;
  };
  __bf16* x2    = (__bf16*)carve((size_t)bs * D_MODEL * 2);
  __bf16* wqkv  = (__bf16*)carve((size_t)3 * D_MODEL * D_MODEL * 2);
  __bf16* wo_b  = (__bf16*)carve((size_t)D_MODEL * D_MODEL * 2);
  __bf16* w1_b  = (__bf16*)carve((size_t)DFFN * D_MODEL * 2);
  __bf16* w2_b  = (__bf16*)carve((size_t)D_MODEL * DFFN * 2);
  float*  bqkv  = (float*)carve((size_t)3 * D_MODEL * 4);
  float*  qkv   = (float*)carve((size_t)bs * 3 * D_MODEL * 4);
  __bf16* conc  = (__bf16*)carve((size_t)bs * D_MODEL * 2);
  float*  xres  = (float*)carve((size_t)bs * D_MODEL * 4);
  __bf16* x2b   = (__bf16*)carve((size_t)bs * D_MODEL * 2);
  __bf16* f1    = (__bf16*)carve((size_t)bs * DFFN * 2);

  // 1. prep: weights->bf16 (Wq/Wk/Wv packed [1536][512]) + bias pack + LN1
  Segs6 cs;
  cs.s[0] = {Wq, wqkv,                 D_MODEL * D_MODEL / 4};
  cs.s[1] = {Wk, wqkv + D_MODEL * D_MODEL,     D_MODEL * D_MODEL / 4};
  cs.s[2] = {Wv, wqkv + 2 * D_MODEL * D_MODEL, D_MODEL * D_MODEL / 4};
  cs.s[3] = {Wo, wo_b, D_MODEL * D_MODEL / 4};
  cs.s[4] = {W1, w1_b, DFFN * D_MODEL / 4};
  cs.s[5] = {W2, w2_b, D_MODEL * DFFN / 4};
  prep<<<dim3(256, 8), 256, 0, stream>>>(cs, bq, bk, bv, bqkv,
                                         x, alpha1, beta1, x2, bs);

  // 2. Fused QKV GEMM: [512,512] @ [1536,512]^T -> qkv [512][1536] fp32
  wave_gemm<0, 0><<<dim3(3 * D_MODEL / 32, bs / 32), 64, 0, stream>>>(
      x2, D_MODEL, wqkv, D_MODEL, bqkv, nullptr, qkv, 3 * D_MODEL, D_MODEL);

  // 3. Attention (all heads per block, 8 waves) -> concat bf16
  attn_kernel<<<bs, 512, 0, stream>>>(qkv, 3 * D_MODEL, cbk, cbv, mask, conc, s);

  // 4. Wo GEMM + bias + residual(x) -> xres fp32 (256 blocks; reverted wo_ln fusion
  //    — 16-block fused version was latency-bound, R5 post-mortem)
  wave_gemm<0, 0><<<dim3(D_MODEL / 32, bs / 32), 64, 0, stream>>>(
      conc, D_MODEL, wo_b, D_MODEL, bo, x, xres, D_MODEL, D_MODEL);

  // 5. LN2 -> x2b bf16 (128 blocks)
  ln_kernel<<<bs / 4, 256, 0, stream>>>(xres, alpha2, beta2, x2b);

  // 6. FFN1 + ReLU -> f1 bf16
  wave_gemm<1, 1><<<dim3(DFFN / 32, bs / 32), 64, 0, stream>>>(
      x2b, D_MODEL, w1_b, D_MODEL, b1, nullptr, f1, DFFN, D_MODEL);

  // 7. FFN2 + bias + residual(xres) -> d_out fp32
  wave_gemm<0, 0><<<dim3(D_MODEL / 32, bs / 32), 64, 0, stream>>>(
      f1, DFFN, w2_b, DFFN, b2, xres, d_out, D_MODEL, DFFN);
}